// Round 1
// baseline (1147.741 us; speedup 1.0000x reference)
//
#include <hip/hip_runtime.h>

typedef unsigned short u16;
typedef __attribute__((ext_vector_type(4))) float v4f;
typedef __attribute__((ext_vector_type(8))) short v8bf;

__device__ inline u16 f2bf(float f){
  union { float f; unsigned u; } v; v.f = f;
  unsigned r = (v.u + 0x7FFFu + ((v.u >> 16) & 1u)) >> 16;
  return (u16)r;
}

#define GLD_LDS16(gp, lp) \
  __builtin_amdgcn_global_load_lds((const __attribute__((address_space(1))) void*)(gp), \
                                   (__attribute__((address_space(3))) void*)(lp), 16, 0, 0)

// ---------------------------------------------------------------------------
// GEMM: C[M,N] = A[M,K](bf16) * W[N,K](bf16)^T + bias, m97 structure.
// FUSE: 0 = bf16 out, 1 = bf16 out + ReLU, 2 = f32 out
// ---------------------------------------------------------------------------
template<int FUSE>
__global__ __launch_bounds__(256, 2) void gemm_bt(
    const u16* __restrict__ A, const u16* __restrict__ W,
    const float* __restrict__ bias, void* __restrict__ C, int N, int K)
{
  __shared__ u16 lA[128*32];
  __shared__ u16 lB[128*32];
  const int tid = threadIdx.x, lane = tid & 63, wid = tid >> 6;
  const int m0 = blockIdx.y * 128, n0 = blockIdx.x * 128;
  const int wr = wid >> 1, wc = wid & 1;

  v4f zero = {0.f, 0.f, 0.f, 0.f};
  v4f acc[4][4];
  #pragma unroll
  for (int m = 0; m < 4; ++m)
    #pragma unroll
    for (int n = 0; n < 4; ++n) acc[m][n] = zero;

  // staging: 8KB tile = 512 x 16B chunks; chunk c = j*256+tid -> row c>>2, col (c&3)*8
  const u16* Ab = A + (size_t)(m0 + (tid >> 2)) * K + (tid & 3) * 8;
  const u16* Wb = W + (size_t)(n0 + (tid >> 2)) * K + (tid & 3) * 8;
  u16* lAw = lA + wid * 512;  // wave-uniform LDS base (+2048 for j=1)
  u16* lBw = lB + wid * 512;
  const int frag_off = (lane & 15) * 32 + ((lane >> 4) << 3);

  for (int k0 = 0; k0 < K; k0 += 32) {
    GLD_LDS16(Ab + k0,                    lAw);
    GLD_LDS16(Ab + k0 + (size_t)64 * K,   lAw + 2048);
    GLD_LDS16(Wb + k0,                    lBw);
    GLD_LDS16(Wb + k0 + (size_t)64 * K,   lBw + 2048);
    __syncthreads();
    v8bf af[4], bfv[4];
    #pragma unroll
    for (int m = 0; m < 4; ++m) af[m]  = *(const v8bf*)&lA[(wr*64 + m*16)*32 + frag_off];
    #pragma unroll
    for (int n = 0; n < 4; ++n) bfv[n] = *(const v8bf*)&lB[(wc*64 + n*16)*32 + frag_off];
    #pragma unroll
    for (int m = 0; m < 4; ++m)
      #pragma unroll
      for (int n = 0; n < 4; ++n)
        acc[m][n] = __builtin_amdgcn_mfma_f32_16x16x32_bf16(af[m], bfv[n], acc[m][n], 0, 0, 0);
    __syncthreads();
  }

  const int cb = n0 + wc * 64 + (lane & 15);
  float bv[4];
  #pragma unroll
  for (int n = 0; n < 4; ++n) bv[n] = bias[cb + n * 16];
  const int r0 = m0 + wr * 64 + ((lane >> 4) << 2);
  #pragma unroll
  for (int m = 0; m < 4; ++m) {
    #pragma unroll
    for (int j = 0; j < 4; ++j) {
      size_t roff = (size_t)(r0 + m * 16 + j) * N;
      #pragma unroll
      for (int n = 0; n < 4; ++n) {
        float v = acc[m][n][j] + bv[n];
        if (FUSE == 1) v = fmaxf(v, 0.f);
        if (FUSE == 2) ((float*)C)[roff + cb + n * 16] = v;
        else           ((u16*)C)[roff + cb + n * 16]   = f2bf(v);
      }
    }
  }
}

// ---------------------------------------------------------------------------
// Fused attention: one WG = one (b,h), 64 query rows; full softmax (no online
// rescale) with gaussian bias folded into the exponent:
//   w = e1*g / (Sg + 1e-5*Z),  e1 = exp(s-m), g = exp(-d^2/32768)
// ---------------------------------------------------------------------------
__global__ __launch_bounds__(256, 1) void attn_k(const u16* __restrict__ qkv,
                                                 u16* __restrict__ o)
{
  __shared__ u16 kv[512 * 72];    // K as [512][72] padded; later V^T as [64][520]
  __shared__ u16 wbuf[64 * 520];  // P (bf16) [64 q rows][512 k] padded
  const int tid = threadIdx.x, lane = tid & 63, wid = tid >> 6;
  const int bh = blockIdx.y, b = bh >> 4, h = bh & 15;
  const int q0 = blockIdx.x * 64;
  const u16* Qg = qkv + (size_t)b * 512 * 3072 + h * 64;
  const u16* Kg = Qg + 1024;
  const u16* Vg = Qg + 2048;

  // stage K -> LDS [kk][d], padded row 72
  #pragma unroll
  for (int it = 0; it < 16; ++it) {
    int c = it * 256 + tid, kk = c >> 3, d0 = (c & 7) * 8;
    *(v8bf*)&kv[kk * 72 + d0] = *(const v8bf*)(Kg + (size_t)kk * 3072 + d0);
  }
  const int qrow = q0 + wid * 16 + (lane & 15);
  const int g8 = (lane >> 4) * 8;
  v8bf qa0 = *(const v8bf*)(Qg + (size_t)qrow * 3072 + g8);
  v8bf qa1 = *(const v8bf*)(Qg + (size_t)qrow * 3072 + 32 + g8);
  __syncthreads();

  v4f zero = {0.f, 0.f, 0.f, 0.f};
  v4f acc[32];
  #pragma unroll
  for (int nb = 0; nb < 32; ++nb) {
    v8bf b0 = *(const v8bf*)&kv[(nb * 16 + (lane & 15)) * 72 + g8];
    v8bf b1 = *(const v8bf*)&kv[(nb * 16 + (lane & 15)) * 72 + 32 + g8];
    v4f t = zero;
    t = __builtin_amdgcn_mfma_f32_16x16x32_bf16(qa0, b0, t, 0, 0, 0);
    t = __builtin_amdgcn_mfma_f32_16x16x32_bf16(qa1, b1, t, 0, 0, 0);
    acc[nb] = t;
  }
  __syncthreads();  // all waves done reading K before V^T overwrites kv

  const int qb = q0 + wid * 16 + ((lane >> 4) << 2);
  const int kb = lane & 15;
  const int wrow = wid * 16 + ((lane >> 4) << 2);
  #pragma unroll
  for (int j = 0; j < 4; ++j) {
    float mx = -1e30f;
    #pragma unroll
    for (int nb = 0; nb < 32; ++nb) mx = fmaxf(mx, acc[nb][j]);
    mx = fmaxf(mx, __shfl_xor(mx, 1));
    mx = fmaxf(mx, __shfl_xor(mx, 2));
    mx = fmaxf(mx, __shfl_xor(mx, 4));
    mx = fmaxf(mx, __shfl_xor(mx, 8));
    mx *= 0.125f;
    float Z = 0.f, Sg = 0.f;
    const float fq = (float)(qb + j);
    #pragma unroll
    for (int nb = 0; nb < 32; ++nb) {
      float s = acc[nb][j] * 0.125f - mx;
      float d = fq - (float)(kb + nb * 16);
      float e1 = __expf(s);
      float e2 = __expf(s - d * d * (1.f / 32768.f));
      Z += e1; Sg += e2;
      acc[nb][j] = e2;
    }
    Z  += __shfl_xor(Z, 1);  Z  += __shfl_xor(Z, 2);  Z  += __shfl_xor(Z, 4);  Z  += __shfl_xor(Z, 8);
    Sg += __shfl_xor(Sg, 1); Sg += __shfl_xor(Sg, 2); Sg += __shfl_xor(Sg, 4); Sg += __shfl_xor(Sg, 8);
    const float inv = 1.f / (Sg + 1e-5f * Z);
    #pragma unroll
    for (int nb = 0; nb < 32; ++nb)
      wbuf[(wrow + j) * 520 + nb * 16 + kb] = f2bf(acc[nb][j] * inv);
  }

  // stage V^T -> kv as [d][kk], padded row 520
  #pragma unroll
  for (int it = 0; it < 16; ++it) {
    int c = it * 256 + tid, kk = c >> 3, d0 = (c & 7) * 8;
    v8bf v = *(const v8bf*)(Vg + (size_t)kk * 3072 + d0);
    #pragma unroll
    for (int x = 0; x < 8; ++x) kv[(d0 + x) * 520 + kk] = (u16)v[x];
  }
  __syncthreads();

  v4f oacc[4];
  #pragma unroll
  for (int n = 0; n < 4; ++n) oacc[n] = zero;
  #pragma unroll
  for (int ks = 0; ks < 16; ++ks) {
    v8bf af = *(const v8bf*)&wbuf[(wid * 16 + (lane & 15)) * 520 + ks * 32 + g8];
    #pragma unroll
    for (int n = 0; n < 4; ++n) {
      v8bf bv = *(const v8bf*)&kv[(n * 16 + (lane & 15)) * 520 + ks * 32 + g8];
      oacc[n] = __builtin_amdgcn_mfma_f32_16x16x32_bf16(af, bv, oacc[n], 0, 0, 0);
    }
  }
  const size_t obase = (size_t)(b * 512 + qb) * 1024 + h * 64;
  #pragma unroll
  for (int n = 0; n < 4; ++n)
    #pragma unroll
    for (int j = 0; j < 4; ++j)
      o[obase + (size_t)j * 1024 + n * 16 + kb] = f2bf(oacc[n][j]);
}

// ---------------------------------------------------------------------------
// LayerNorm(x + r) * g + beta -> y (f32) and yb (bf16). One block per row.
// ---------------------------------------------------------------------------
__global__ __launch_bounds__(256) void ln_res_k(
    const float* __restrict__ x, const float* __restrict__ r,
    const float* __restrict__ g, const float* __restrict__ beta,
    float* __restrict__ y, u16* __restrict__ yb)
{
  const int row = blockIdx.x, tid = threadIdx.x;
  const size_t base = (size_t)row * 1024 + tid * 4;
  float4 xv = *(const float4*)(x + base);
  float4 rv = *(const float4*)(r + base);
  float v0 = xv.x + rv.x, v1 = xv.y + rv.y, v2 = xv.z + rv.z, v3 = xv.w + rv.w;
  float s = v0 + v1 + v2 + v3;
  float q = v0*v0 + v1*v1 + v2*v2 + v3*v3;
  #pragma unroll
  for (int m = 1; m < 64; m <<= 1) { s += __shfl_xor(s, m); q += __shfl_xor(q, m); }
  __shared__ float ls[4], lq[4];
  if ((tid & 63) == 0) { ls[tid >> 6] = s; lq[tid >> 6] = q; }
  __syncthreads();
  s = ls[0] + ls[1] + ls[2] + ls[3];
  q = lq[0] + lq[1] + lq[2] + lq[3];
  const float mu = s * (1.f / 1024.f);
  const float var = q * (1.f / 1024.f) - mu * mu;
  const float rs = rsqrtf(var + 1e-5f);
  const int e = tid * 4;
  float o0 = (v0 - mu) * rs * g[e]     + beta[e];
  float o1 = (v1 - mu) * rs * g[e + 1] + beta[e + 1];
  float o2 = (v2 - mu) * rs * g[e + 2] + beta[e + 2];
  float o3 = (v3 - mu) * rs * g[e + 3] + beta[e + 3];
  *(float4*)(y + base) = make_float4(o0, o1, o2, o3);
  ushort4 ob; ob.x = f2bf(o0); ob.y = f2bf(o1); ob.z = f2bf(o2); ob.w = f2bf(o3);
  *(ushort4*)(yb + base) = ob;
}

// x = src + pe(batch, e); pe depends on BATCH index per the reference.
__global__ __launch_bounds__(256) void pe_add_k(const float* __restrict__ src,
    float* __restrict__ xf, u16* __restrict__ xb)
{
  const int idx = blockIdx.x * 256 + threadIdx.x;
  const int e = idx & 1023;
  const int b = idx >> 19;  // idx / (512*1024)
  float freq = __expf((float)(e >> 1) * (-18.420680743952367f * (1.f / 1024.f)));
  float ang = (float)b * freq;
  float pe = (e & 1) ? cosf(ang) : sinf(ang);
  float v = src[idx] + pe;
  xf[idx] = v;
  xb[idx] = f2bf(v);
}

__global__ __launch_bounds__(256) void cvt_k(const float* __restrict__ s,
                                             u16* __restrict__ d, int n4)
{
  int i = blockIdx.x * 256 + threadIdx.x;
  if (i >= n4) return;
  float4 v = ((const float4*)s)[i];
  ushort4 ov; ov.x = f2bf(v.x); ov.y = f2bf(v.y); ov.z = f2bf(v.z); ov.w = f2bf(v.w);
  ((ushort4*)d)[i] = ov;
}

__global__ __launch_bounds__(256) void head_k(const float* __restrict__ xf,
    const float* __restrict__ hw, const float* __restrict__ hb, float* __restrict__ out)
{
  const int b = blockIdx.x, tid = threadIdx.x;
  const float4 xv = ((const float4*)(xf + ((size_t)b * 512 + 511) * 1024))[tid];
  const float4 wv = ((const float4*)hw)[tid];
  float s = xv.x * wv.x + xv.y * wv.y + xv.z * wv.z + xv.w * wv.w;
  #pragma unroll
  for (int m = 1; m < 64; m <<= 1) s += __shfl_xor(s, m);
  __shared__ float ls[4];
  if ((tid & 63) == 0) ls[tid >> 6] = s;
  __syncthreads();
  if (tid == 0) out[b] = ls[0] + ls[1] + ls[2] + ls[3] + hb[0];
}

// ---------------------------------------------------------------------------
extern "C" void kernel_launch(void* const* d_in, const int* in_sizes, int n_in,
                              void* d_out, int out_size, void* d_ws, size_t ws_size,
                              hipStream_t stream)
{
  const float* src  = (const float*)d_in[0];
  const float* ipw  = (const float*)d_in[1];
  const float* ipb  = (const float*)d_in[2];
  const float* outw = (const float*)d_in[3];
  const float* outb = (const float*)d_in[4];
  const float* f1w  = (const float*)d_in[5];
  const float* f1b  = (const float*)d_in[6];
  const float* f2w  = (const float*)d_in[7];
  const float* f2b  = (const float*)d_in[8];
  const float* l1g  = (const float*)d_in[9];
  const float* l1b  = (const float*)d_in[10];
  const float* l2g  = (const float*)d_in[11];
  const float* l2b  = (const float*)d_in[12];
  const float* hw   = (const float*)d_in[13];
  const float* hb   = (const float*)d_in[14];

  char* p = (char*)d_ws;
  auto take = [&](size_t bytes) { char* r = p; p += (bytes + 255) & ~(size_t)255; return r; };
  float* xf   = (float*)take(4096ull * 1024 * 4);   // f32 activation master
  u16*   xb   = (u16*)  take(4096ull * 1024 * 2);   // bf16 copy for GEMM A
  u16*   qkvb = (u16*)  take(4096ull * 3072 * 2);
  u16*   ob   = (u16*)  take(4096ull * 1024 * 2);   // attention output
  float* pf   = (float*)take(4096ull * 1024 * 4);   // proj / ff2 f32 result
  u16*   f1o  = (u16*)  take(4096ull * 4096 * 2);   // ff1 activation
  u16*   wc   = (u16*)  take(4096ull * 1024 * 2);   // bf16 weight scratch (8.4MB)

  pe_add_k<<<16384, 256, 0, stream>>>(src, xf, xb);

  for (int l = 0; l < 4; ++l) {
    cvt_k<<<3072 * 1024 / 1024, 256, 0, stream>>>(ipw + (size_t)l * 3072 * 1024, wc, 3072 * 1024 / 4);
    gemm_bt<0><<<dim3(24, 32), 256, 0, stream>>>(xb, wc, ipb + l * 3072, qkvb, 3072, 1024);
    attn_k<<<dim3(8, 128), 256, 0, stream>>>(qkvb, ob);
    cvt_k<<<1024 * 1024 / 1024, 256, 0, stream>>>(outw + (size_t)l * 1024 * 1024, wc, 1024 * 1024 / 4);
    gemm_bt<2><<<dim3(8, 32), 256, 0, stream>>>(ob, wc, outb + l * 1024, pf, 1024, 1024);
    ln_res_k<<<4096, 256, 0, stream>>>(xf, pf, l1g + l * 1024, l1b + l * 1024, xf, xb);
    cvt_k<<<4096 * 1024 / 1024, 256, 0, stream>>>(f1w + (size_t)l * 4096 * 1024, wc, 4096 * 1024 / 4);
    gemm_bt<1><<<dim3(32, 32), 256, 0, stream>>>(xb, wc, f1b + l * 4096, f1o, 4096, 1024);
    cvt_k<<<4096 * 1024 / 1024, 256, 0, stream>>>(f2w + (size_t)l * 1024 * 4096, wc, 1024 * 4096 / 4);
    gemm_bt<2><<<dim3(8, 32), 256, 0, stream>>>(f1o, wc, f2b + l * 1024, pf, 1024, 4096);
    ln_res_k<<<4096, 256, 0, stream>>>(xf, pf, l2g + l * 1024, l2b + l * 1024, xf, xb);
  }
  head_k<<<8, 256, 0, stream>>>(xf, hw, hb, (float*)d_out);
}

// Round 2
// 1112.119 us; speedup vs baseline: 1.0320x; 1.0320x over previous
//
#include <hip/hip_runtime.h>

typedef unsigned short u16;
typedef __attribute__((ext_vector_type(4))) float v4f;
typedef __attribute__((ext_vector_type(8))) short v8bf;

__device__ inline u16 f2bf(float f){
  union { float f; unsigned u; } v; v.f = f;
  unsigned r = (v.u + 0x7FFFu + ((v.u >> 16) & 1u)) >> 16;
  return (u16)r;
}

#define GLD_LDS16(gp, lp) \
  __builtin_amdgcn_global_load_lds((const __attribute__((address_space(1))) void*)(gp), \
                                   (__attribute__((address_space(3))) void*)(lp), 16, 0, 0)
#define VMCNT(n) asm volatile("s_waitcnt vmcnt(" #n ")" ::: "memory")
#define LGKM0 do { asm volatile("s_waitcnt lgkmcnt(0)" ::: "memory"); \
                   __builtin_amdgcn_sched_barrier(0); } while (0)

// ---------------------------------------------------------------------------
// GEMM2: C[M=4096,N] = A[M,K](bf16) * W[N,K](bf16)^T (+bias)
// 256x256 tile, 8 waves (2x4), BK=32, ring-4 LDS (128KB), counted vmcnt(8).
// LDS layout fragment-major: slot | A: frag f(0..15) lane l -> 16B ; B at +8192.
// FUSE: 0 = bf16+bias, 1 = bf16+bias+ReLU, 2 = f32 raw split-K partial (no bias)
// ---------------------------------------------------------------------------
template<int FUSE>
__global__ __launch_bounds__(512, 2) void gemm2(
    const u16* __restrict__ A, const u16* __restrict__ W,
    const float* __restrict__ bias, void* __restrict__ C,
    int N, int K, int Kc, int gx, int gy)
{
  __shared__ u16 smem[65536];  // 4 slots x 32KB
  const int tid = threadIdx.x, lane = tid & 63, wid = tid >> 6;
  const int wm = wid >> 2, wn = wid & 3;

  const int nwg = gridDim.x, bid = blockIdx.x;
  const int swz = (bid & 7) * (nwg >> 3) + (bid >> 3);  // nwg % 8 == 0 always
  const int gxy = gx * gy;
  const int bz = swz / gxy;
  const int rem = swz - bz * gxy;
  const int by = rem / gx;
  const int bx = rem - by * gx;

  const int k0 = bz * Kc;
  const int KT = Kc >> 5;  // BK=32, KT >= 8 for all our shapes

  // staging source pointers: unit u = p*512+tid -> frag f = p*8+wid, lane
  const int ar = by * 256 + wid * 16 + (lane & 15);
  const int br = bx * 256 + wid * 16 + (lane & 15);
  const int kc8 = (lane >> 4) * 8;
  const u16* pA0 = A + (size_t)ar * K + k0 + kc8;
  const u16* pA1 = pA0 + (size_t)128 * K;
  const u16* pB0 = W + (size_t)br * K + k0 + kc8;
  const u16* pB1 = pB0 + (size_t)128 * K;
  u16* dst = smem + tid * 8;  // linear: wave-uniform base + lane*16B

  auto stage = [&](int t) {
    u16* s = dst + (t & 3) * 16384;
    const int ko = t * 32;
    GLD_LDS16(pA0 + ko, s);
    GLD_LDS16(pA1 + ko, s + 4096);
    GLD_LDS16(pB0 + ko, s + 8192);
    GLD_LDS16(pB1 + ko, s + 12288);
  };

  v4f acc[8][4];
  #pragma unroll
  for (int i = 0; i < 8; ++i)
    #pragma unroll
    for (int j = 0; j < 4; ++j) acc[i][j] = (v4f){0.f, 0.f, 0.f, 0.f};

  stage(0); stage(1); stage(2);

  const u16* aRd = smem + ((size_t)(wm * 8) * 64 + lane) * 8;
  const u16* bRd = smem + 8192 + ((size_t)(wn * 4) * 64 + lane) * 8;

#define GEMM_BODY(VMN, DOSTAGE)                                                 \
  {                                                                             \
    VMCNT(VMN);                                                                 \
    __builtin_amdgcn_s_barrier();                                               \
    __builtin_amdgcn_sched_barrier(0);                                          \
    const u16* as = aRd + (t & 3) * 16384;                                      \
    const u16* bs = bRd + (t & 3) * 16384;                                      \
    v8bf af[8], bf4[4];                                                         \
    _Pragma("unroll") for (int i = 0; i < 8; ++i)                               \
        af[i] = *(const v8bf*)(as + i * 512);                                   \
    _Pragma("unroll") for (int j = 0; j < 4; ++j)                               \
        bf4[j] = *(const v8bf*)(bs + j * 512);                                  \
    if (DOSTAGE) stage(t + 3);                                                  \
    LGKM0;                                                                      \
    __builtin_amdgcn_s_setprio(1);                                              \
    _Pragma("unroll") for (int i = 0; i < 8; ++i)                               \
      _Pragma("unroll") for (int j = 0; j < 4; ++j)                             \
        acc[i][j] = __builtin_amdgcn_mfma_f32_16x16x32_bf16(af[i], bf4[j],      \
                                                            acc[i][j], 0, 0, 0);\
    __builtin_amdgcn_s_setprio(0);                                              \
  }

  int t = 0;
  for (; t < KT - 3; ++t) GEMM_BODY(8, true);
  GEMM_BODY(8, false); ++t;
  GEMM_BODY(4, false); ++t;
  GEMM_BODY(0, false);
#undef GEMM_BODY

  const int cn0 = bx * 256 + wn * 64 + (lane & 15);
  const int rm0 = by * 256 + wm * 128 + ((lane >> 4) << 2);
  if (FUSE == 2) {
    float* Cp = (float*)C + (size_t)bz * 4096 * N;
    #pragma unroll
    for (int i = 0; i < 8; ++i)
      #pragma unroll
      for (int r = 0; r < 4; ++r) {
        size_t ro = (size_t)(rm0 + i * 16 + r) * N + cn0;
        #pragma unroll
        for (int j = 0; j < 4; ++j) Cp[ro + j * 16] = acc[i][j][r];
      }
  } else {
    float bv[4];
    #pragma unroll
    for (int j = 0; j < 4; ++j) bv[j] = bias[cn0 + j * 16];
    u16* Cp = (u16*)C;
    #pragma unroll
    for (int i = 0; i < 8; ++i)
      #pragma unroll
      for (int r = 0; r < 4; ++r) {
        size_t ro = (size_t)(rm0 + i * 16 + r) * N + cn0;
        #pragma unroll
        for (int j = 0; j < 4; ++j) {
          float v = acc[i][j][r] + bv[j];
          if (FUSE == 1) v = fmaxf(v, 0.f);
          Cp[ro + j * 16] = f2bf(v);
        }
      }
  }
}

// ---------------------------------------------------------------------------
// Fused attention: one WG = one (b,h), 64 query rows (unchanged, verified R1)
// ---------------------------------------------------------------------------
__global__ __launch_bounds__(256, 1) void attn_k(const u16* __restrict__ qkv,
                                                 u16* __restrict__ o)
{
  __shared__ u16 kv[512 * 72];    // K as [512][72] padded; later V^T as [64][520]
  __shared__ u16 wbuf[64 * 520];  // P (bf16) [64 q rows][512 k] padded
  const int tid = threadIdx.x, lane = tid & 63, wid = tid >> 6;
  const int bh = blockIdx.y, b = bh >> 4, h = bh & 15;
  const int q0 = blockIdx.x * 64;
  const u16* Qg = qkv + (size_t)b * 512 * 3072 + h * 64;
  const u16* Kg = Qg + 1024;
  const u16* Vg = Qg + 2048;

  #pragma unroll
  for (int it = 0; it < 16; ++it) {
    int c = it * 256 + tid, kk = c >> 3, d0 = (c & 7) * 8;
    *(v8bf*)&kv[kk * 72 + d0] = *(const v8bf*)(Kg + (size_t)kk * 3072 + d0);
  }
  const int qrow = q0 + wid * 16 + (lane & 15);
  const int g8 = (lane >> 4) * 8;
  v8bf qa0 = *(const v8bf*)(Qg + (size_t)qrow * 3072 + g8);
  v8bf qa1 = *(const v8bf*)(Qg + (size_t)qrow * 3072 + 32 + g8);
  __syncthreads();

  v4f zero = {0.f, 0.f, 0.f, 0.f};
  v4f acc[32];
  #pragma unroll
  for (int nb = 0; nb < 32; ++nb) {
    v8bf b0 = *(const v8bf*)&kv[(nb * 16 + (lane & 15)) * 72 + g8];
    v8bf b1 = *(const v8bf*)&kv[(nb * 16 + (lane & 15)) * 72 + 32 + g8];
    v4f t = zero;
    t = __builtin_amdgcn_mfma_f32_16x16x32_bf16(qa0, b0, t, 0, 0, 0);
    t = __builtin_amdgcn_mfma_f32_16x16x32_bf16(qa1, b1, t, 0, 0, 0);
    acc[nb] = t;
  }
  __syncthreads();

  const int qb = q0 + wid * 16 + ((lane >> 4) << 2);
  const int kb = lane & 15;
  const int wrow = wid * 16 + ((lane >> 4) << 2);
  #pragma unroll
  for (int j = 0; j < 4; ++j) {
    float mx = -1e30f;
    #pragma unroll
    for (int nb = 0; nb < 32; ++nb) mx = fmaxf(mx, acc[nb][j]);
    mx = fmaxf(mx, __shfl_xor(mx, 1));
    mx = fmaxf(mx, __shfl_xor(mx, 2));
    mx = fmaxf(mx, __shfl_xor(mx, 4));
    mx = fmaxf(mx, __shfl_xor(mx, 8));
    mx *= 0.125f;
    float Z = 0.f, Sg = 0.f;
    const float fq = (float)(qb + j);
    #pragma unroll
    for (int nb = 0; nb < 32; ++nb) {
      float s = acc[nb][j] * 0.125f - mx;
      float d = fq - (float)(kb + nb * 16);
      float e1 = __expf(s);
      float e2 = __expf(s - d * d * (1.f / 32768.f));
      Z += e1; Sg += e2;
      acc[nb][j] = e2;
    }
    Z  += __shfl_xor(Z, 1);  Z  += __shfl_xor(Z, 2);  Z  += __shfl_xor(Z, 4);  Z  += __shfl_xor(Z, 8);
    Sg += __shfl_xor(Sg, 1); Sg += __shfl_xor(Sg, 2); Sg += __shfl_xor(Sg, 4); Sg += __shfl_xor(Sg, 8);
    const float inv = 1.f / (Sg + 1e-5f * Z);
    #pragma unroll
    for (int nb = 0; nb < 32; ++nb)
      wbuf[(wrow + j) * 520 + nb * 16 + kb] = f2bf(acc[nb][j] * inv);
  }

  #pragma unroll
  for (int it = 0; it < 16; ++it) {
    int c = it * 256 + tid, kk = c >> 3, d0 = (c & 7) * 8;
    v8bf v = *(const v8bf*)(Vg + (size_t)kk * 3072 + d0);
    #pragma unroll
    for (int x = 0; x < 8; ++x) kv[(d0 + x) * 520 + kk] = (u16)v[x];
  }
  __syncthreads();

  v4f oacc[4];
  #pragma unroll
  for (int n = 0; n < 4; ++n) oacc[n] = zero;
  #pragma unroll
  for (int ks = 0; ks < 16; ++ks) {
    v8bf af = *(const v8bf*)&wbuf[(wid * 16 + (lane & 15)) * 520 + ks * 32 + g8];
    #pragma unroll
    for (int n = 0; n < 4; ++n) {
      v8bf bv = *(const v8bf*)&kv[(n * 16 + (lane & 15)) * 520 + ks * 32 + g8];
      oacc[n] = __builtin_amdgcn_mfma_f32_16x16x32_bf16(af, bv, oacc[n], 0, 0, 0);
    }
  }
  const size_t obase = (size_t)(b * 512 + qb) * 1024 + h * 64;
  #pragma unroll
  for (int n = 0; n < 4; ++n)
    #pragma unroll
    for (int j = 0; j < 4; ++j)
      o[obase + (size_t)j * 1024 + n * 16 + kb] = f2bf(oacc[n][j]);
}

// ---------------------------------------------------------------------------
// LayerNorm(x + bias + part0 + part1) * g + beta -> y (f32) and yb (bf16)
// ---------------------------------------------------------------------------
__global__ __launch_bounds__(256) void ln_res2_k(
    const float* __restrict__ x, const float* __restrict__ part,
    const float* __restrict__ bias, const float* __restrict__ g,
    const float* __restrict__ beta, float* __restrict__ y, u16* __restrict__ yb)
{
  const int row = blockIdx.x, tid = threadIdx.x;
  const size_t base = (size_t)row * 1024 + tid * 4;
  const size_t MN = 4096ull * 1024;
  float4 xv = *(const float4*)(x + base);
  float4 p0 = *(const float4*)(part + base);
  float4 p1 = *(const float4*)(part + MN + base);
  const int e = tid * 4;
  float4 bb = *(const float4*)(bias + e);
  float v0 = xv.x + p0.x + p1.x + bb.x;
  float v1 = xv.y + p0.y + p1.y + bb.y;
  float v2 = xv.z + p0.z + p1.z + bb.z;
  float v3 = xv.w + p0.w + p1.w + bb.w;
  float s = v0 + v1 + v2 + v3;
  float q = v0*v0 + v1*v1 + v2*v2 + v3*v3;
  #pragma unroll
  for (int m = 1; m < 64; m <<= 1) { s += __shfl_xor(s, m); q += __shfl_xor(q, m); }
  __shared__ float ls[4], lq[4];
  if ((tid & 63) == 0) { ls[tid >> 6] = s; lq[tid >> 6] = q; }
  __syncthreads();
  s = ls[0] + ls[1] + ls[2] + ls[3];
  q = lq[0] + lq[1] + lq[2] + lq[3];
  const float mu = s * (1.f / 1024.f);
  const float var = q * (1.f / 1024.f) - mu * mu;
  const float rs = rsqrtf(var + 1e-5f);
  float4 gv = *(const float4*)(g + e);
  float4 be = *(const float4*)(beta + e);
  float o0 = (v0 - mu) * rs * gv.x + be.x;
  float o1 = (v1 - mu) * rs * gv.y + be.y;
  float o2 = (v2 - mu) * rs * gv.z + be.z;
  float o3 = (v3 - mu) * rs * gv.w + be.w;
  *(float4*)(y + base) = make_float4(o0, o1, o2, o3);
  ushort4 ob; ob.x = f2bf(o0); ob.y = f2bf(o1); ob.z = f2bf(o2); ob.w = f2bf(o3);
  *(ushort4*)(yb + base) = ob;
}

__global__ __launch_bounds__(256) void pe_add_k(const float* __restrict__ src,
    float* __restrict__ xf, u16* __restrict__ xb)
{
  const int idx = blockIdx.x * 256 + threadIdx.x;
  const int e = idx & 1023;
  const int b = idx >> 19;
  float freq = __expf((float)(e >> 1) * (-18.420680743952367f * (1.f / 1024.f)));
  float ang = (float)b * freq;
  float pe = (e & 1) ? cosf(ang) : sinf(ang);
  float v = src[idx] + pe;
  xf[idx] = v;
  xb[idx] = f2bf(v);
}

__global__ __launch_bounds__(256) void cvt_k(const float* __restrict__ s,
                                             u16* __restrict__ d, int n4)
{
  int i = blockIdx.x * 256 + threadIdx.x;
  if (i >= n4) return;
  float4 v = ((const float4*)s)[i];
  ushort4 ov; ov.x = f2bf(v.x); ov.y = f2bf(v.y); ov.z = f2bf(v.z); ov.w = f2bf(v.w);
  ((ushort4*)d)[i] = ov;
}

__global__ __launch_bounds__(256) void head_k(const float* __restrict__ xf,
    const float* __restrict__ hw, const float* __restrict__ hb, float* __restrict__ out)
{
  const int b = blockIdx.x, tid = threadIdx.x;
  const float4 xv = ((const float4*)(xf + ((size_t)b * 512 + 511) * 1024))[tid];
  const float4 wv = ((const float4*)hw)[tid];
  float s = xv.x * wv.x + xv.y * wv.y + xv.z * wv.z + xv.w * wv.w;
  #pragma unroll
  for (int m = 1; m < 64; m <<= 1) s += __shfl_xor(s, m);
  __shared__ float ls[4];
  if ((tid & 63) == 0) ls[tid >> 6] = s;
  __syncthreads();
  if (tid == 0) out[b] = ls[0] + ls[1] + ls[2] + ls[3] + hb[0];
}

// ---------------------------------------------------------------------------
extern "C" void kernel_launch(void* const* d_in, const int* in_sizes, int n_in,
                              void* d_out, int out_size, void* d_ws, size_t ws_size,
                              hipStream_t stream)
{
  const float* src  = (const float*)d_in[0];
  const float* ipw  = (const float*)d_in[1];
  const float* ipb  = (const float*)d_in[2];
  const float* outw = (const float*)d_in[3];
  const float* outb = (const float*)d_in[4];
  const float* f1w  = (const float*)d_in[5];
  const float* f1b  = (const float*)d_in[6];
  const float* f2w  = (const float*)d_in[7];
  const float* f2b  = (const float*)d_in[8];
  const float* l1g  = (const float*)d_in[9];
  const float* l1b  = (const float*)d_in[10];
  const float* l2g  = (const float*)d_in[11];
  const float* l2b  = (const float*)d_in[12];
  const float* hw   = (const float*)d_in[13];
  const float* hb   = (const float*)d_in[14];

  char* p = (char*)d_ws;
  auto take = [&](size_t bytes) { char* r = p; p += (bytes + 255) & ~(size_t)255; return r; };
  float* xf   = (float*)take(4096ull * 1024 * 4);   // f32 activation master
  u16*   xb   = (u16*)  take(4096ull * 1024 * 2);   // bf16 copy for GEMM A
  u16*   qkvb = (u16*)  take(4096ull * 3072 * 2);
  u16*   ob   = (u16*)  take(4096ull * 1024 * 2);   // attention output
  float* pf   = (float*)take(2ull * 4096 * 1024 * 4); // split-K=2 f32 partials
  u16*   f1o  = (u16*)  take(4096ull * 4096 * 2);   // ff1 activation
  u16*   wc   = (u16*)  take(4096ull * 1024 * 2);   // bf16 weight scratch

  pe_add_k<<<16384, 256, 0, stream>>>(src, xf, xb);

  for (int l = 0; l < 4; ++l) {
    // QKV: [4096,3072] = xb * ipw^T + bias, bf16 out
    cvt_k<<<3072 * 1024 / 1024, 256, 0, stream>>>(ipw + (size_t)l * 3072 * 1024, wc, 3072 * 1024 / 4);
    gemm2<0><<<192, 512, 0, stream>>>(xb, wc, ipb + l * 3072, qkvb, 3072, 1024, 1024, 12, 16);
    attn_k<<<dim3(8, 128), 256, 0, stream>>>(qkvb, ob);
    // out-proj: split-K=2 f32 partials -> ln_res2 reduces
    cvt_k<<<1024 * 1024 / 1024, 256, 0, stream>>>(outw + (size_t)l * 1024 * 1024, wc, 1024 * 1024 / 4);
    gemm2<2><<<128, 512, 0, stream>>>(ob, wc, nullptr, pf, 1024, 1024, 512, 4, 16);
    ln_res2_k<<<4096, 256, 0, stream>>>(xf, pf, outb + l * 1024, l1g + l * 1024, l1b + l * 1024, xf, xb);
    // FF1: [4096,4096] bf16 + ReLU
    cvt_k<<<4096 * 1024 / 1024, 256, 0, stream>>>(f1w + (size_t)l * 4096 * 1024, wc, 4096 * 1024 / 4);
    gemm2<1><<<256, 512, 0, stream>>>(xb, wc, f1b + l * 4096, f1o, 4096, 1024, 1024, 16, 16);
    // FF2: split-K=2 f32 partials -> ln_res2 reduces
    cvt_k<<<4096 * 1024 / 1024, 256, 0, stream>>>(f2w + (size_t)l * 1024 * 4096, wc, 1024 * 4096 / 4);
    gemm2<2><<<128, 512, 0, stream>>>(f1o, wc, nullptr, pf, 1024, 4096, 2048, 4, 16);
    ln_res2_k<<<4096, 256, 0, stream>>>(xf, pf, f2b + l * 1024, l2g + l * 1024, l2b + l * 1024, xf, xb);
  }
  head_k<<<8, 256, 0, stream>>>(xf, hw, hb, (float*)d_out);
}

// Round 3
// 1008.720 us; speedup vs baseline: 1.1378x; 1.1025x over previous
//
#include <hip/hip_runtime.h>

typedef unsigned short u16;
typedef __attribute__((ext_vector_type(4))) float v4f;
typedef __attribute__((ext_vector_type(8))) short v8bf;

__device__ inline u16 f2bf(float f){
  union { float f; unsigned u; } v; v.f = f;
  unsigned r = (v.u + 0x7FFFu + ((v.u >> 16) & 1u)) >> 16;
  return (u16)r;
}
__device__ inline float bf2f(u16 u){
  union { unsigned u; float f; } v; v.u = ((unsigned)u) << 16;
  return v.f;
}

#define GLD_LDS16(gp, lp) \
  __builtin_amdgcn_global_load_lds((const __attribute__((address_space(1))) void*)(gp), \
                                   (__attribute__((address_space(3))) void*)(lp), 16, 0, 0)
#define VMCNT(n) asm volatile("s_waitcnt vmcnt(" #n ")" ::: "memory")
#define LGKM0 do { asm volatile("s_waitcnt lgkmcnt(0)" ::: "memory"); \
                   __builtin_amdgcn_sched_barrier(0); } while (0)

// ---------------------------------------------------------------------------
// gemm8: C[4096,N] = A[4096,K](bf16) * W[N,K](bf16)^T (+bias), 8-phase schedule.
// 256x256 tile, BK=64, 8 waves (2M x 4N), LDS 2 x {A0,A1,B0,B1} x 16KB = 128KB.
// Fragment-major regions: frag f = i_local*2+kk, lane l -> 16B chunk (f*64+l).
// Per tile t: 4 phases = C-quadrants (0,0),(0,1),(1,1),(1,0); 16 MFMA each.
// Staging: B(t+1) @ t.p0, A(t+2) @ t.p3; boundary vmcnt(4) (0 at t==NT-2).
// FUSE: 0 = bf16+bias, 1 = bf16+bias+ReLU, 2 = bf16 split-K partial (no bias)
// ---------------------------------------------------------------------------
template<int FUSE>
__global__ __launch_bounds__(512, 2) void gemm8(
    const u16* __restrict__ A, const u16* __restrict__ W,
    const float* __restrict__ bias, void* __restrict__ C,
    int N, int K, int Kc, int gx, int gy)
{
  __shared__ u16 smem[65536];  // 2 x 64KB buffers; regions A0,A1,B0,B1 (8192 u16 each)
  const int tid = threadIdx.x, lane = tid & 63, wid = tid >> 6;
  const int wm = wid >> 2, wn = wid & 3;

  const int nwg = gridDim.x, bid = blockIdx.x;
  const int swz = (bid & 7) * (nwg >> 3) + (bid >> 3);
  const int gxy = gx * gy;
  const int bz = swz / gxy;
  const int rem = swz - bz * gxy;
  const int by = rem / gx;
  const int bx = rem - by * gx;
  const int k0 = bz * Kc;
  const int NT = Kc >> 6;

  // staging: thread covers frag f = u*8+wid (u=0,1) of each 128x64 half
  const int arow = (wid >> 1) * 16 + (lane & 15);
  const int akk  = (wid & 1) * 32 + ((lane >> 4) << 3);
  const u16* gA = A + (size_t)(by * 256 + arow) * K + k0 + akk;
  const u16* gB = W + (size_t)(bx * 256 + arow) * K + k0 + akk;
  u16* ldst = smem + tid * 8;

  auto stageA = [&](int t, int h) {  // A half h -> region h
    u16* d = ldst + (t & 1) * 32768 + h * 8192;
    const u16* s = gA + (size_t)(h * 128) * K + t * 64;
    GLD_LDS16(s, d);
    GLD_LDS16(s + (size_t)64 * K, d + 4096);
  };
  auto stageB = [&](int t, int h) {  // B half h -> region 2+h
    u16* d = ldst + (t & 1) * 32768 + (2 + h) * 8192;
    const u16* s = gB + (size_t)(h * 128) * K + t * 64;
    GLD_LDS16(s, d);
    GLD_LDS16(s + (size_t)64 * K, d + 4096);
  };

  v4f acc[8][4];
  #pragma unroll
  for (int i = 0; i < 8; ++i)
    #pragma unroll
    for (int j = 0; j < 4; ++j) acc[i][j] = (v4f){0.f, 0.f, 0.f, 0.f};

  // prologue: all of t0, A halves of t1; keep A(t1) in flight
  stageA(0, 0); stageB(0, 0); stageB(0, 1); stageA(0, 1);
  if (NT > 1) { stageA(1, 0); stageA(1, 1); }
  if (NT > 2) { VMCNT(4); } else { VMCNT(0); }
  __builtin_amdgcn_s_barrier();

  const u16* rdA = smem + wm * 8192 + lane * 8;
  const u16* rdB = smem + 16384 + (wn >> 1) * 8192 + lane * 8;
  const int jb = (wn & 1) * 4;

  v8bf aq[4][2], bq[2][2];

#define PHASE(QI, QJ, LOADA, LOADB, STAGE_CODE, VM_CODE)                        \
  {                                                                             \
    const int bufo = (t & 1) * 32768;                                           \
    if (LOADA) {                                                                \
      _Pragma("unroll") for (int m = 0; m < 4; ++m)                             \
        _Pragma("unroll") for (int kk = 0; kk < 2; ++kk)                        \
          aq[m][kk] = *(const v8bf*)(rdA + bufo + (((QI)*4 + m)*2 + kk)*512);   \
    }                                                                           \
    if (LOADB) {                                                                \
      _Pragma("unroll") for (int n = 0; n < 2; ++n)                             \
        _Pragma("unroll") for (int kk = 0; kk < 2; ++kk)                        \
          bq[n][kk] = *(const v8bf*)(rdB + bufo + ((jb + (QJ)*2 + n)*2 + kk)*512);\
    }                                                                           \
    STAGE_CODE;                                                                 \
    VM_CODE;                                                                    \
    __builtin_amdgcn_s_barrier();                                               \
    LGKM0;                                                                      \
    __builtin_amdgcn_s_setprio(1);                                              \
    _Pragma("unroll") for (int m = 0; m < 4; ++m)                               \
      _Pragma("unroll") for (int n = 0; n < 2; ++n)                             \
        _Pragma("unroll") for (int kk = 0; kk < 2; ++kk)                        \
          acc[(QI)*4 + m][(QJ)*2 + n] = __builtin_amdgcn_mfma_f32_16x16x32_bf16(\
              aq[m][kk], bq[n][kk], acc[(QI)*4 + m][(QJ)*2 + n], 0, 0, 0);      \
    __builtin_amdgcn_s_setprio(0);                                              \
    __builtin_amdgcn_s_barrier();                                               \
  }

  for (int t = 0; t < NT; ++t) {
    PHASE(0, 0, true,  true,
          { if (t + 1 < NT) { stageB(t + 1, 0); stageB(t + 1, 1); } }, {});
    PHASE(0, 1, false, true,  {}, {});
    PHASE(1, 1, true,  false, {}, {});
    PHASE(1, 0, false, true,
          { if (t + 2 < NT) { stageA(t + 2, 0); stageA(t + 2, 1); } },
          { if (t == NT - 2) { VMCNT(0); } else if (t < NT - 2) { VMCNT(4); } });
  }
#undef PHASE

  const int cn0 = bx * 256 + wn * 64 + (lane & 15);
  const int rm0 = by * 256 + wm * 128 + ((lane >> 4) << 2);
  if (FUSE == 2) {
    u16* Cp = (u16*)C + (size_t)bz * 4096 * N;
    #pragma unroll
    for (int i = 0; i < 8; ++i)
      #pragma unroll
      for (int r = 0; r < 4; ++r) {
        size_t ro = (size_t)(rm0 + i * 16 + r) * N + cn0;
        #pragma unroll
        for (int j = 0; j < 4; ++j) Cp[ro + j * 16] = f2bf(acc[i][j][r]);
      }
  } else {
    float bv[4];
    #pragma unroll
    for (int j = 0; j < 4; ++j) bv[j] = bias[cn0 + j * 16];
    u16* Cp = (u16*)C;
    #pragma unroll
    for (int i = 0; i < 8; ++i)
      #pragma unroll
      for (int r = 0; r < 4; ++r) {
        size_t ro = (size_t)(rm0 + i * 16 + r) * N + cn0;
        #pragma unroll
        for (int j = 0; j < 4; ++j) {
          float v = acc[i][j][r] + bv[j];
          if (FUSE == 1) v = fmaxf(v, 0.f);
          Cp[ro + j * 16] = f2bf(v);
        }
      }
  }
}

// ---------------------------------------------------------------------------
// Fused attention (unchanged, verified R1/R2)
// ---------------------------------------------------------------------------
__global__ __launch_bounds__(256, 1) void attn_k(const u16* __restrict__ qkv,
                                                 u16* __restrict__ o)
{
  __shared__ u16 kv[512 * 72];
  __shared__ u16 wbuf[64 * 520];
  const int tid = threadIdx.x, lane = tid & 63, wid = tid >> 6;
  const int bh = blockIdx.y, b = bh >> 4, h = bh & 15;
  const int q0 = blockIdx.x * 64;
  const u16* Qg = qkv + (size_t)b * 512 * 3072 + h * 64;
  const u16* Kg = Qg + 1024;
  const u16* Vg = Qg + 2048;

  #pragma unroll
  for (int it = 0; it < 16; ++it) {
    int c = it * 256 + tid, kk = c >> 3, d0 = (c & 7) * 8;
    *(v8bf*)&kv[kk * 72 + d0] = *(const v8bf*)(Kg + (size_t)kk * 3072 + d0);
  }
  const int qrow = q0 + wid * 16 + (lane & 15);
  const int g8 = (lane >> 4) * 8;
  v8bf qa0 = *(const v8bf*)(Qg + (size_t)qrow * 3072 + g8);
  v8bf qa1 = *(const v8bf*)(Qg + (size_t)qrow * 3072 + 32 + g8);
  __syncthreads();

  v4f zero = {0.f, 0.f, 0.f, 0.f};
  v4f acc[32];
  #pragma unroll
  for (int nb = 0; nb < 32; ++nb) {
    v8bf b0 = *(const v8bf*)&kv[(nb * 16 + (lane & 15)) * 72 + g8];
    v8bf b1 = *(const v8bf*)&kv[(nb * 16 + (lane & 15)) * 72 + 32 + g8];
    v4f t = zero;
    t = __builtin_amdgcn_mfma_f32_16x16x32_bf16(qa0, b0, t, 0, 0, 0);
    t = __builtin_amdgcn_mfma_f32_16x16x32_bf16(qa1, b1, t, 0, 0, 0);
    acc[nb] = t;
  }
  __syncthreads();

  const int qb = q0 + wid * 16 + ((lane >> 4) << 2);
  const int kb = lane & 15;
  const int wrow = wid * 16 + ((lane >> 4) << 2);
  #pragma unroll
  for (int j = 0; j < 4; ++j) {
    float mx = -1e30f;
    #pragma unroll
    for (int nb = 0; nb < 32; ++nb) mx = fmaxf(mx, acc[nb][j]);
    mx = fmaxf(mx, __shfl_xor(mx, 1));
    mx = fmaxf(mx, __shfl_xor(mx, 2));
    mx = fmaxf(mx, __shfl_xor(mx, 4));
    mx = fmaxf(mx, __shfl_xor(mx, 8));
    mx *= 0.125f;
    float Z = 0.f, Sg = 0.f;
    const float fq = (float)(qb + j);
    #pragma unroll
    for (int nb = 0; nb < 32; ++nb) {
      float s = acc[nb][j] * 0.125f - mx;
      float d = fq - (float)(kb + nb * 16);
      float e1 = __expf(s);
      float e2 = __expf(s - d * d * (1.f / 32768.f));
      Z += e1; Sg += e2;
      acc[nb][j] = e2;
    }
    Z  += __shfl_xor(Z, 1);  Z  += __shfl_xor(Z, 2);  Z  += __shfl_xor(Z, 4);  Z  += __shfl_xor(Z, 8);
    Sg += __shfl_xor(Sg, 1); Sg += __shfl_xor(Sg, 2); Sg += __shfl_xor(Sg, 4); Sg += __shfl_xor(Sg, 8);
    const float inv = 1.f / (Sg + 1e-5f * Z);
    #pragma unroll
    for (int nb = 0; nb < 32; ++nb)
      wbuf[(wrow + j) * 520 + nb * 16 + kb] = f2bf(acc[nb][j] * inv);
  }

  #pragma unroll
  for (int it = 0; it < 16; ++it) {
    int c = it * 256 + tid, kk = c >> 3, d0 = (c & 7) * 8;
    v8bf v = *(const v8bf*)(Vg + (size_t)kk * 3072 + d0);
    #pragma unroll
    for (int x = 0; x < 8; ++x) kv[(d0 + x) * 520 + kk] = (u16)v[x];
  }
  __syncthreads();

  v4f oacc[4];
  #pragma unroll
  for (int n = 0; n < 4; ++n) oacc[n] = zero;
  #pragma unroll
  for (int ks = 0; ks < 16; ++ks) {
    v8bf af = *(const v8bf*)&wbuf[(wid * 16 + (lane & 15)) * 520 + ks * 32 + g8];
    #pragma unroll
    for (int n = 0; n < 4; ++n) {
      v8bf bv = *(const v8bf*)&kv[(n * 16 + (lane & 15)) * 520 + ks * 32 + g8];
      oacc[n] = __builtin_amdgcn_mfma_f32_16x16x32_bf16(af, bv, oacc[n], 0, 0, 0);
    }
  }
  const size_t obase = (size_t)(b * 512 + qb) * 1024 + h * 64;
  #pragma unroll
  for (int n = 0; n < 4; ++n)
    #pragma unroll
    for (int j = 0; j < 4; ++j)
      o[obase + (size_t)j * 1024 + n * 16 + kb] = f2bf(oacc[n][j]);
}

// ---------------------------------------------------------------------------
// LayerNorm(x + bias + sum of 4 bf16 partials) * g + beta -> y (f32), yb (bf16)
// ---------------------------------------------------------------------------
__global__ __launch_bounds__(256) void ln_res4_k(
    const float* __restrict__ x, const u16* __restrict__ part,
    const float* __restrict__ bias, const float* __restrict__ g,
    const float* __restrict__ beta, float* __restrict__ y, u16* __restrict__ yb)
{
  const int row = blockIdx.x, tid = threadIdx.x;
  const size_t base = (size_t)row * 1024 + tid * 4;
  const size_t MN = 4096ull * 1024;
  float4 xv = *(const float4*)(x + base);
  const int e = tid * 4;
  float4 bb = *(const float4*)(bias + e);
  float v0 = xv.x + bb.x, v1 = xv.y + bb.y, v2 = xv.z + bb.z, v3 = xv.w + bb.w;
  #pragma unroll
  for (int q = 0; q < 4; ++q) {
    ushort4 pv = *(const ushort4*)(part + q * MN + base);
    v0 += bf2f(pv.x); v1 += bf2f(pv.y); v2 += bf2f(pv.z); v3 += bf2f(pv.w);
  }
  float s = v0 + v1 + v2 + v3;
  float q2 = v0*v0 + v1*v1 + v2*v2 + v3*v3;
  #pragma unroll
  for (int m = 1; m < 64; m <<= 1) { s += __shfl_xor(s, m); q2 += __shfl_xor(q2, m); }
  __shared__ float ls[4], lq[4];
  if ((tid & 63) == 0) { ls[tid >> 6] = s; lq[tid >> 6] = q2; }
  __syncthreads();
  s = ls[0] + ls[1] + ls[2] + ls[3];
  q2 = lq[0] + lq[1] + lq[2] + lq[3];
  const float mu = s * (1.f / 1024.f);
  const float var = q2 * (1.f / 1024.f) - mu * mu;
  const float rs = rsqrtf(var + 1e-5f);
  float4 gv = *(const float4*)(g + e);
  float4 be = *(const float4*)(beta + e);
  float o0 = (v0 - mu) * rs * gv.x + be.x;
  float o1 = (v1 - mu) * rs * gv.y + be.y;
  float o2 = (v2 - mu) * rs * gv.z + be.z;
  float o3 = (v3 - mu) * rs * gv.w + be.w;
  *(float4*)(y + base) = make_float4(o0, o1, o2, o3);
  ushort4 ob; ob.x = f2bf(o0); ob.y = f2bf(o1); ob.z = f2bf(o2); ob.w = f2bf(o3);
  *(ushort4*)(yb + base) = ob;
}

__global__ __launch_bounds__(256) void pe_add_k(const float* __restrict__ src,
    float* __restrict__ xf, u16* __restrict__ xb)
{
  const int idx = blockIdx.x * 256 + threadIdx.x;
  const int e = idx & 1023;
  const int b = idx >> 19;
  float freq = __expf((float)(e >> 1) * (-18.420680743952367f * (1.f / 1024.f)));
  float ang = (float)b * freq;
  float pe = (e & 1) ? cosf(ang) : sinf(ang);
  float v = src[idx] + pe;
  xf[idx] = v;
  xb[idx] = f2bf(v);
}

__global__ __launch_bounds__(256) void cvt_k(const float* __restrict__ s,
                                             u16* __restrict__ d, int n4)
{
  int i = blockIdx.x * 256 + threadIdx.x;
  if (i >= n4) return;
  float4 v = ((const float4*)s)[i];
  ushort4 ov; ov.x = f2bf(v.x); ov.y = f2bf(v.y); ov.z = f2bf(v.z); ov.w = f2bf(v.w);
  ((ushort4*)d)[i] = ov;
}

__global__ __launch_bounds__(256) void head_k(const float* __restrict__ xf,
    const float* __restrict__ hw, const float* __restrict__ hb, float* __restrict__ out)
{
  const int b = blockIdx.x, tid = threadIdx.x;
  const float4 xv = ((const float4*)(xf + ((size_t)b * 512 + 511) * 1024))[tid];
  const float4 wv = ((const float4*)hw)[tid];
  float s = xv.x * wv.x + xv.y * wv.y + xv.z * wv.z + xv.w * wv.w;
  #pragma unroll
  for (int m = 1; m < 64; m <<= 1) s += __shfl_xor(s, m);
  __shared__ float ls[4];
  if ((tid & 63) == 0) ls[tid >> 6] = s;
  __syncthreads();
  if (tid == 0) out[b] = ls[0] + ls[1] + ls[2] + ls[3] + hb[0];
}

// ---------------------------------------------------------------------------
extern "C" void kernel_launch(void* const* d_in, const int* in_sizes, int n_in,
                              void* d_out, int out_size, void* d_ws, size_t ws_size,
                              hipStream_t stream)
{
  const float* src  = (const float*)d_in[0];
  const float* ipw  = (const float*)d_in[1];
  const float* ipb  = (const float*)d_in[2];
  const float* outw = (const float*)d_in[3];
  const float* outb = (const float*)d_in[4];
  const float* f1w  = (const float*)d_in[5];
  const float* f1b  = (const float*)d_in[6];
  const float* f2w  = (const float*)d_in[7];
  const float* f2b  = (const float*)d_in[8];
  const float* l1g  = (const float*)d_in[9];
  const float* l1b  = (const float*)d_in[10];
  const float* l2g  = (const float*)d_in[11];
  const float* l2b  = (const float*)d_in[12];
  const float* hw   = (const float*)d_in[13];
  const float* hb   = (const float*)d_in[14];

  char* p = (char*)d_ws;
  auto take = [&](size_t bytes) { char* r = p; p += (bytes + 255) & ~(size_t)255; return r; };
  float* xf   = (float*)take(4096ull * 1024 * 4);     // f32 activation master
  u16*   xb   = (u16*)  take(4096ull * 1024 * 2);     // bf16 activation copy
  u16*   slA  = (u16*)  take(4096ull * 4096 * 2);     // qkvb (QKV out) / f1o (FF1 out)
  u16*   ob   = (u16*)  take(4096ull * 1024 * 2);     // attention output
  u16*   pf   = (u16*)  take(4ull * 4096 * 1024 * 2); // 4 bf16 split-K partials
  u16*   wc   = (u16*)  take(4096ull * 1024 * 2);     // bf16 weight scratch

  u16* qkvb = slA;
  u16* f1o  = slA;

  pe_add_k<<<16384, 256, 0, stream>>>(src, xf, xb);

  for (int l = 0; l < 4; ++l) {
    // QKV: [4096,3072], K=1024, no split
    cvt_k<<<3072, 256, 0, stream>>>(ipw + (size_t)l * 3072 * 1024, wc, 3072 * 1024 / 4);
    gemm8<0><<<192, 512, 0, stream>>>(xb, wc, ipb + l * 3072, qkvb, 3072, 1024, 1024, 12, 16);
    attn_k<<<dim3(8, 128), 256, 0, stream>>>(qkvb, ob);
    // out-proj: N=1024, K=1024, split-K=4 -> bf16 partials
    cvt_k<<<1024, 256, 0, stream>>>(outw + (size_t)l * 1024 * 1024, wc, 1024 * 1024 / 4);
    gemm8<2><<<256, 512, 0, stream>>>(ob, wc, nullptr, pf, 1024, 1024, 256, 4, 16);
    ln_res4_k<<<4096, 256, 0, stream>>>(xf, pf, outb + l * 1024, l1g + l * 1024, l1b + l * 1024, xf, xb);
    // FF1: [4096,4096], K=1024, no split, ReLU
    cvt_k<<<4096, 256, 0, stream>>>(f1w + (size_t)l * 4096 * 1024, wc, 4096 * 1024 / 4);
    gemm8<1><<<256, 512, 0, stream>>>(xb, wc, f1b + l * 4096, f1o, 4096, 1024, 1024, 16, 16);
    // FF2: N=1024, K=4096, split-K=4 -> bf16 partials
    cvt_k<<<4096, 256, 0, stream>>>(f2w + (size_t)l * 1024 * 4096, wc, 1024 * 4096 / 4);
    gemm8<2><<<256, 512, 0, stream>>>(f1o, wc, nullptr, pf, 1024, 4096, 1024, 4, 16);
    ln_res4_k<<<4096, 256, 0, stream>>>(xf, pf, f2b + l * 1024, l2g + l * 1024, l2b + l * 1024, xf, xb);
  }
  head_k<<<8, 256, 0, stream>>>(xf, hw, hb, (float*)d_out);
}

// Round 4
// 910.794 us; speedup vs baseline: 1.2602x; 1.1075x over previous
//
#include <hip/hip_runtime.h>

typedef unsigned short u16;
typedef __attribute__((ext_vector_type(4))) float v4f;
typedef __attribute__((ext_vector_type(8))) short v8bf;

__device__ inline u16 f2bf(float f){
  union { float f; unsigned u; } v; v.f = f;
  unsigned r = (v.u + 0x7FFFu + ((v.u >> 16) & 1u)) >> 16;
  return (u16)r;
}
__device__ inline float bf2f(u16 u){
  union { unsigned u; float f; } v; v.u = ((unsigned)u) << 16;
  return v.f;
}

#define GLD_LDS16(gp, lp) \
  __builtin_amdgcn_global_load_lds((const __attribute__((address_space(1))) void*)(gp), \
                                   (__attribute__((address_space(3))) void*)(lp), 16, 0, 0)
#define VMCNT(n) asm volatile("s_waitcnt vmcnt(" #n ")" ::: "memory")
#define LGKM0 do { asm volatile("s_waitcnt lgkmcnt(0)" ::: "memory"); \
                   __builtin_amdgcn_sched_barrier(0); } while (0)

// ---------------------------------------------------------------------------
// gemm8 (unchanged from R3): 256x256 tile, BK=64, 8-phase, counted vmcnt.
// FUSE: 0 = bf16+bias, 1 = bf16+bias+ReLU, 2 = bf16 split-K partial (no bias)
// ---------------------------------------------------------------------------
template<int FUSE>
__global__ __launch_bounds__(512, 2) void gemm8(
    const u16* __restrict__ A, const u16* __restrict__ W,
    const float* __restrict__ bias, void* __restrict__ C,
    int N, int K, int Kc, int gx, int gy)
{
  __shared__ u16 smem[65536];
  const int tid = threadIdx.x, lane = tid & 63, wid = tid >> 6;
  const int wm = wid >> 2, wn = wid & 3;

  const int nwg = gridDim.x, bid = blockIdx.x;
  const int swz = (bid & 7) * (nwg >> 3) + (bid >> 3);
  const int gxy = gx * gy;
  const int bz = swz / gxy;
  const int rem = swz - bz * gxy;
  const int by = rem / gx;
  const int bx = rem - by * gx;
  const int k0 = bz * Kc;
  const int NT = Kc >> 6;

  const int arow = (wid >> 1) * 16 + (lane & 15);
  const int akk  = (wid & 1) * 32 + ((lane >> 4) << 3);
  const u16* gA = A + (size_t)(by * 256 + arow) * K + k0 + akk;
  const u16* gB = W + (size_t)(bx * 256 + arow) * K + k0 + akk;
  u16* ldst = smem + tid * 8;

  auto stageA = [&](int t, int h) {
    u16* d = ldst + (t & 1) * 32768 + h * 8192;
    const u16* s = gA + (size_t)(h * 128) * K + t * 64;
    GLD_LDS16(s, d);
    GLD_LDS16(s + (size_t)64 * K, d + 4096);
  };
  auto stageB = [&](int t, int h) {
    u16* d = ldst + (t & 1) * 32768 + (2 + h) * 8192;
    const u16* s = gB + (size_t)(h * 128) * K + t * 64;
    GLD_LDS16(s, d);
    GLD_LDS16(s + (size_t)64 * K, d + 4096);
  };

  v4f acc[8][4];
  #pragma unroll
  for (int i = 0; i < 8; ++i)
    #pragma unroll
    for (int j = 0; j < 4; ++j) acc[i][j] = (v4f){0.f, 0.f, 0.f, 0.f};

  stageA(0, 0); stageB(0, 0); stageB(0, 1); stageA(0, 1);
  if (NT > 1) { stageA(1, 0); stageA(1, 1); }
  if (NT > 2) { VMCNT(4); } else { VMCNT(0); }
  __builtin_amdgcn_s_barrier();

  const u16* rdA = smem + wm * 8192 + lane * 8;
  const u16* rdB = smem + 16384 + (wn >> 1) * 8192 + lane * 8;
  const int jb = (wn & 1) * 4;

  v8bf aq[4][2], bq[2][2];

#define PHASE(QI, QJ, LOADA, LOADB, STAGE_CODE, VM_CODE)                        \
  {                                                                             \
    const int bufo = (t & 1) * 32768;                                           \
    if (LOADA) {                                                                \
      _Pragma("unroll") for (int m = 0; m < 4; ++m)                             \
        _Pragma("unroll") for (int kk = 0; kk < 2; ++kk)                        \
          aq[m][kk] = *(const v8bf*)(rdA + bufo + (((QI)*4 + m)*2 + kk)*512);   \
    }                                                                           \
    if (LOADB) {                                                                \
      _Pragma("unroll") for (int n = 0; n < 2; ++n)                             \
        _Pragma("unroll") for (int kk = 0; kk < 2; ++kk)                        \
          bq[n][kk] = *(const v8bf*)(rdB + bufo + ((jb + (QJ)*2 + n)*2 + kk)*512);\
    }                                                                           \
    STAGE_CODE;                                                                 \
    VM_CODE;                                                                    \
    __builtin_amdgcn_s_barrier();                                               \
    LGKM0;                                                                      \
    __builtin_amdgcn_s_setprio(1);                                              \
    _Pragma("unroll") for (int m = 0; m < 4; ++m)                               \
      _Pragma("unroll") for (int n = 0; n < 2; ++n)                             \
        _Pragma("unroll") for (int kk = 0; kk < 2; ++kk)                        \
          acc[(QI)*4 + m][(QJ)*2 + n] = __builtin_amdgcn_mfma_f32_16x16x32_bf16(\
              aq[m][kk], bq[n][kk], acc[(QI)*4 + m][(QJ)*2 + n], 0, 0, 0);      \
    __builtin_amdgcn_s_setprio(0);                                              \
    __builtin_amdgcn_s_barrier();                                               \
  }

  for (int t = 0; t < NT; ++t) {
    PHASE(0, 0, true,  true,
          { if (t + 1 < NT) { stageB(t + 1, 0); stageB(t + 1, 1); } }, {});
    PHASE(0, 1, false, true,  {}, {});
    PHASE(1, 1, true,  false, {}, {});
    PHASE(1, 0, false, true,
          { if (t + 2 < NT) { stageA(t + 2, 0); stageA(t + 2, 1); } },
          { if (t == NT - 2) { VMCNT(0); } else if (t < NT - 2) { VMCNT(4); } });
  }
#undef PHASE

  const int cn0 = bx * 256 + wn * 64 + (lane & 15);
  const int rm0 = by * 256 + wm * 128 + ((lane >> 4) << 2);
  if (FUSE == 2) {
    u16* Cp = (u16*)C + (size_t)bz * 4096 * N;
    #pragma unroll
    for (int i = 0; i < 8; ++i)
      #pragma unroll
      for (int r = 0; r < 4; ++r) {
        size_t ro = (size_t)(rm0 + i * 16 + r) * N + cn0;
        #pragma unroll
        for (int j = 0; j < 4; ++j) Cp[ro + j * 16] = f2bf(acc[i][j][r]);
      }
  } else {
    float bv[4];
    #pragma unroll
    for (int j = 0; j < 4; ++j) bv[j] = bias[cn0 + j * 16];
    u16* Cp = (u16*)C;
    #pragma unroll
    for (int i = 0; i < 8; ++i)
      #pragma unroll
      for (int r = 0; r < 4; ++r) {
        size_t ro = (size_t)(rm0 + i * 16 + r) * N + cn0;
        #pragma unroll
        for (int j = 0; j < 4; ++j) {
          float v = acc[i][j][r] + bv[j];
          if (FUSE == 1) v = fmaxf(v, 0.f);
          Cp[ro + j * 16] = f2bf(v);
        }
      }
  }
}

// ---------------------------------------------------------------------------
// attn_f: flash-tiled fused attention. WG = 256 thr (4 waves), 64 q-rows,
// 8 KV-tiles of 64. K double-buffered frag-major via global_load_lds;
// V^T reg-staged into XOR-swizzled frag-major LDS; online softmax in s'-space
// (gaussian bias folded: s' = s/8 - d^2/32768, single exp). Counted vmcnt(2).
// ---------------------------------------------------------------------------
__global__ __launch_bounds__(256, 2) void attn_f(const u16* __restrict__ qkv,
                                                 u16* __restrict__ o)
{
  __shared__ u16 Kf[2][4096];   // 8 frags x 64 lanes x 16B, per buffer
  __shared__ u16 Vt[2][4096];   // V^T frag-major, XOR-swizzled
  __shared__ u16 wbuf[64 * 72]; // P tile [64 q][64 k], col XOR-swizzled
  const int tid = threadIdx.x, lane = tid & 63, wid = tid >> 6;
  const int grp = lane >> 4, li = lane & 15;
  const int bh = blockIdx.y, b = bh >> 4, h = bh & 15;
  const int q0 = blockIdx.x * 64;
  const u16* Qg = qkv + (size_t)b * 512 * 3072 + h * 64;
  const u16* Kg = Qg + 1024;
  const u16* Vg = Qg + 2048;

  // Q fragments (persistent)
  const size_t qrow = (size_t)(q0 + wid * 16 + li) * 3072;
  v8bf qa0 = *(const v8bf*)(Qg + qrow + grp * 8);
  v8bf qa1 = *(const v8bf*)(Qg + qrow + 32 + grp * 8);

  // K staging: wave wid stages frags f = wid*2 + {0,1}  (nb = wid, kk = s)
  const u16* kga = Kg + (size_t)(wid * 16 + li) * 3072 + grp * 8;
  auto k_stage = [&](int kt, int buf) {
    #pragma unroll
    for (int s = 0; s < 2; ++s)
      GLD_LDS16(kga + (size_t)kt * 64 * 3072 + s * 32, &Kf[buf][(wid * 2 + s) * 512]);
  };
  // V row load (thread chunk u = x*256+tid: row kk = u>>3, d0 = (u&7)*8)
  auto v_load = [&](int kt, int x) -> v8bf {
    int u = x * 256 + tid, kk = u >> 3, d0 = (u & 7) * 8;
    return *(const v8bf*)(Vg + (size_t)(kt * 64 + kk) * 3072 + d0);
  };
  auto vt_write = [&](int buf, int x, v8bf v) {
    int u = x * 256 + tid, kk = u >> 3, d0 = (u & 7) * 8;
    int kg = (kk >> 3) & 3, kks = kk >> 5, jb2 = (kk & 7) * 2;
    #pragma unroll
    for (int i = 0; i < 8; ++i) {
      int d = d0 + i;
      int byte = (((d >> 4) * 2 + kks) * 1024 + ((d & 15) + 16 * kg) * 16 + jb2)
                 ^ (((d >> 4) & 3) << 5);
      *(u16*)((char*)&Vt[buf][0] + byte) = (u16)v[i];
    }
  };

  v4f oacc[4];
  #pragma unroll
  for (int nt = 0; nt < 4; ++nt) oacc[nt] = (v4f){0.f, 0.f, 0.f, 0.f};
  float mreg[4] = {-1e30f, -1e30f, -1e30f, -1e30f};
  float sg[4] = {0.f, 0.f, 0.f, 0.f};
  float fqv[4];
  #pragma unroll
  for (int j = 0; j < 4; ++j) fqv[j] = (float)(q0 + wid * 16 + grp * 4 + j);

  v8bf vst[2][2];
  // prologue
  k_stage(0, 0);
  k_stage(1, 1);
  vst[0][0] = v_load(0, 0); vst[0][1] = v_load(0, 1);
  VMCNT(0);
  vt_write(0, 0, vst[0][0]); vt_write(0, 1, vst[0][1]);
  vst[1][0] = v_load(1, 0); vst[1][1] = v_load(1, 1);
  LGKM0;
  __builtin_amdgcn_s_barrier();

  const float GC = 3.0517578125e-05f;  // 1/32768

  #pragma unroll
  for (int t = 0; t < 8; ++t) {
    const int cur = t & 1;
    // ---- QK^T ----
    v8bf bq0[4], bq1[4];
    #pragma unroll
    for (int nb = 0; nb < 4; ++nb) {
      bq0[nb] = *(const v8bf*)&Kf[cur][(nb * 2 + 0) * 512 + lane * 8];
      bq1[nb] = *(const v8bf*)&Kf[cur][(nb * 2 + 1) * 512 + lane * 8];
    }
    v4f pa[4];
    #pragma unroll
    for (int nb = 0; nb < 4; ++nb) {
      v4f z = (v4f){0.f, 0.f, 0.f, 0.f};
      z = __builtin_amdgcn_mfma_f32_16x16x32_bf16(qa0, bq0[nb], z, 0, 0, 0);
      pa[nb] = __builtin_amdgcn_mfma_f32_16x16x32_bf16(qa1, bq1[nb], z, 0, 0, 0);
    }
    if (t < 7) {
      __builtin_amdgcn_s_barrier();   // Kf[cur] free for restage; Vt[(t+1)&1] free
      __builtin_amdgcn_sched_barrier(0);
      if (t + 2 < 8) k_stage(t + 2, cur);
      if (t < 6) { VMCNT(2); } else { VMCNT(0); }   // V(t+1) landed
      vt_write((t + 1) & 1, 0, vst[(t + 1) & 1][0]);
      vt_write((t + 1) & 1, 1, vst[(t + 1) & 1][1]);
      if (t + 2 < 8) { vst[t & 1][0] = v_load(t + 2, 0); vst[t & 1][1] = v_load(t + 2, 1); }
    }
    // ---- online softmax in s'-space ----
    #pragma unroll
    for (int nb = 0; nb < 4; ++nb) {
      const float fk = (float)(t * 64 + nb * 16 + li);
      #pragma unroll
      for (int j = 0; j < 4; ++j) {
        float d = fqv[j] - fk;
        pa[nb][j] = pa[nb][j] * 0.125f - d * d * GC;
      }
    }
    #pragma unroll
    for (int j = 0; j < 4; ++j) {
      float tmax = fmaxf(fmaxf(pa[0][j], pa[1][j]), fmaxf(pa[2][j], pa[3][j]));
      tmax = fmaxf(tmax, __shfl_xor(tmax, 1));
      tmax = fmaxf(tmax, __shfl_xor(tmax, 2));
      tmax = fmaxf(tmax, __shfl_xor(tmax, 4));
      tmax = fmaxf(tmax, __shfl_xor(tmax, 8));
      float mn = fmaxf(mreg[j], tmax);
      float sc = __expf(mreg[j] - mn);
      mreg[j] = mn;
      float rs = 0.f;
      #pragma unroll
      for (int nb = 0; nb < 4; ++nb) {
        float e = __expf(pa[nb][j] - mn);
        pa[nb][j] = e;
        rs += e;
      }
      rs += __shfl_xor(rs, 1); rs += __shfl_xor(rs, 2);
      rs += __shfl_xor(rs, 4); rs += __shfl_xor(rs, 8);
      sg[j] = sg[j] * sc + rs;
      #pragma unroll
      for (int nt = 0; nt < 4; ++nt) oacc[nt][j] *= sc;
    }
    // store P (bf16, unnormalized) with col XOR swizzle
    #pragma unroll
    for (int j = 0; j < 4; ++j) {
      const int row = wid * 16 + grp * 4 + j;
      #pragma unroll
      for (int nb = 0; nb < 4; ++nb)
        wbuf[row * 72 + ((nb * 16 + li) ^ (grp << 3))] = f2bf(pa[nb][j]);
    }
    // ---- PV ----
    const int swr = ((li >> 2) & 3) << 3;
    v8bf af0 = *(const v8bf*)&wbuf[(wid * 16 + li) * 72 + ((0 * 32 + grp * 8) ^ swr)];
    v8bf af1 = *(const v8bf*)&wbuf[(wid * 16 + li) * 72 + ((1 * 32 + grp * 8) ^ swr)];
    #pragma unroll
    for (int nt = 0; nt < 4; ++nt) {
      v8bf bv0 = *(const v8bf*)((char*)&Vt[cur][0] + ((((nt * 2 + 0) * 1024) + lane * 16) ^ ((nt & 3) << 5)));
      v8bf bv1 = *(const v8bf*)((char*)&Vt[cur][0] + ((((nt * 2 + 1) * 1024) + lane * 16) ^ ((nt & 3) << 5)));
      oacc[nt] = __builtin_amdgcn_mfma_f32_16x16x32_bf16(af0, bv0, oacc[nt], 0, 0, 0);
      oacc[nt] = __builtin_amdgcn_mfma_f32_16x16x32_bf16(af1, bv1, oacc[nt], 0, 0, 0);
    }
    if (t < 7) {
      if (t < 6) { VMCNT(2); } else { VMCNT(0); }   // K(t+2) landed
      LGKM0;
      __builtin_amdgcn_s_barrier();
      __builtin_amdgcn_sched_barrier(0);
    }
  }

  // epilogue: normalize and store
  float rin[4];
  #pragma unroll
  for (int j = 0; j < 4; ++j) rin[j] = 1.f / sg[j];
  const size_t obase = (size_t)(b * 512 + q0 + wid * 16 + grp * 4) * 1024 + h * 64;
  #pragma unroll
  for (int nt = 0; nt < 4; ++nt)
    #pragma unroll
    for (int j = 0; j < 4; ++j)
      o[obase + (size_t)j * 1024 + nt * 16 + li] = f2bf(oacc[nt][j] * rin[j]);
}

// ---------------------------------------------------------------------------
// LayerNorm(x + bias + sum of 4 bf16 partials) * g + beta -> y (f32), yb (bf16)
// ---------------------------------------------------------------------------
__global__ __launch_bounds__(256) void ln_res4_k(
    const float* __restrict__ x, const u16* __restrict__ part,
    const float* __restrict__ bias, const float* __restrict__ g,
    const float* __restrict__ beta, float* __restrict__ y, u16* __restrict__ yb)
{
  const int row = blockIdx.x, tid = threadIdx.x;
  const size_t base = (size_t)row * 1024 + tid * 4;
  const size_t MN = 4096ull * 1024;
  float4 xv = *(const float4*)(x + base);
  const int e = tid * 4;
  float4 bb = *(const float4*)(bias + e);
  float v0 = xv.x + bb.x, v1 = xv.y + bb.y, v2 = xv.z + bb.z, v3 = xv.w + bb.w;
  #pragma unroll
  for (int q = 0; q < 4; ++q) {
    ushort4 pv = *(const ushort4*)(part + q * MN + base);
    v0 += bf2f(pv.x); v1 += bf2f(pv.y); v2 += bf2f(pv.z); v3 += bf2f(pv.w);
  }
  float s = v0 + v1 + v2 + v3;
  float q2 = v0*v0 + v1*v1 + v2*v2 + v3*v3;
  #pragma unroll
  for (int m = 1; m < 64; m <<= 1) { s += __shfl_xor(s, m); q2 += __shfl_xor(q2, m); }
  __shared__ float ls[4], lq[4];
  if ((tid & 63) == 0) { ls[tid >> 6] = s; lq[tid >> 6] = q2; }
  __syncthreads();
  s = ls[0] + ls[1] + ls[2] + ls[3];
  q2 = lq[0] + lq[1] + lq[2] + lq[3];
  const float mu = s * (1.f / 1024.f);
  const float var = q2 * (1.f / 1024.f) - mu * mu;
  const float rs = rsqrtf(var + 1e-5f);
  float4 gv = *(const float4*)(g + e);
  float4 be = *(const float4*)(beta + e);
  float o0 = (v0 - mu) * rs * gv.x + be.x;
  float o1 = (v1 - mu) * rs * gv.y + be.y;
  float o2 = (v2 - mu) * rs * gv.z + be.z;
  float o3 = (v3 - mu) * rs * gv.w + be.w;
  *(float4*)(y + base) = make_float4(o0, o1, o2, o3);
  ushort4 ob; ob.x = f2bf(o0); ob.y = f2bf(o1); ob.z = f2bf(o2); ob.w = f2bf(o3);
  *(ushort4*)(yb + base) = ob;
}

__global__ __launch_bounds__(256) void pe_add_k(const float* __restrict__ src,
    float* __restrict__ xf, u16* __restrict__ xb)
{
  const int idx = blockIdx.x * 256 + threadIdx.x;
  const int e = idx & 1023;
  const int b = idx >> 19;
  float freq = __expf((float)(e >> 1) * (-18.420680743952367f * (1.f / 1024.f)));
  float ang = (float)b * freq;
  float pe = (e & 1) ? cosf(ang) : sinf(ang);
  float v = src[idx] + pe;
  xf[idx] = v;
  xb[idx] = f2bf(v);
}

// convert one layer's 4 weight matrices f32 -> bf16 in a single launch
__global__ __launch_bounds__(256) void cvt4_k(const float* __restrict__ s0,
    const float* __restrict__ s1, const float* __restrict__ s2,
    const float* __restrict__ s3, u16* __restrict__ dst)
{
  int i = blockIdx.x * 256 + threadIdx.x;  // float4 index, total 3145728
  const float* s; size_t off;
  if (i < 786432)       { s = s0; off = (size_t)i; }
  else if (i < 1048576) { s = s1; off = (size_t)i - 786432; }
  else if (i < 2097152) { s = s2; off = (size_t)i - 1048576; }
  else                  { s = s3; off = (size_t)i - 2097152; }
  float4 v = ((const float4*)s)[off];
  ushort4 ov; ov.x = f2bf(v.x); ov.y = f2bf(v.y); ov.z = f2bf(v.z); ov.w = f2bf(v.w);
  ((ushort4*)dst)[i] = ov;
}

__global__ __launch_bounds__(256) void head_k(const float* __restrict__ xf,
    const float* __restrict__ hw, const float* __restrict__ hb, float* __restrict__ out)
{
  const int b = blockIdx.x, tid = threadIdx.x;
  const float4 xv = ((const float4*)(xf + ((size_t)b * 512 + 511) * 1024))[tid];
  const float4 wv = ((const float4*)hw)[tid];
  float s = xv.x * wv.x + xv.y * wv.y + xv.z * wv.z + xv.w * wv.w;
  #pragma unroll
  for (int m = 1; m < 64; m <<= 1) s += __shfl_xor(s, m);
  __shared__ float ls[4];
  if ((tid & 63) == 0) ls[tid >> 6] = s;
  __syncthreads();
  if (tid == 0) out[b] = ls[0] + ls[1] + ls[2] + ls[3] + hb[0];
}

// ---------------------------------------------------------------------------
extern "C" void kernel_launch(void* const* d_in, const int* in_sizes, int n_in,
                              void* d_out, int out_size, void* d_ws, size_t ws_size,
                              hipStream_t stream)
{
  const float* src  = (const float*)d_in[0];
  const float* ipw  = (const float*)d_in[1];
  const float* ipb  = (const float*)d_in[2];
  const float* outw = (const float*)d_in[3];
  const float* outb = (const float*)d_in[4];
  const float* f1w  = (const float*)d_in[5];
  const float* f1b  = (const float*)d_in[6];
  const float* f2w  = (const float*)d_in[7];
  const float* f2b  = (const float*)d_in[8];
  const float* l1g  = (const float*)d_in[9];
  const float* l1b  = (const float*)d_in[10];
  const float* l2g  = (const float*)d_in[11];
  const float* l2b  = (const float*)d_in[12];
  const float* hw   = (const float*)d_in[13];
  const float* hb   = (const float*)d_in[14];

  char* p = (char*)d_ws;
  auto take = [&](size_t bytes) { char* r = p; p += (bytes + 255) & ~(size_t)255; return r; };
  float* xf   = (float*)take(4096ull * 1024 * 4);     // f32 activation master
  u16*   xb   = (u16*)  take(4096ull * 1024 * 2);     // bf16 activation copy
  u16*   slA  = (u16*)  take(4096ull * 4096 * 2);     // qkvb / f1o
  u16*   ob   = (u16*)  take(4096ull * 1024 * 2);     // attention output
  u16*   pf   = (u16*)  take(4ull * 4096 * 1024 * 2); // 4 bf16 split-K partials
  u16*   wc   = (u16*)  take(12582912ull * 2);        // bf16 weights, one layer

  u16* qkvb = slA;
  u16* f1o  = slA;

  pe_add_k<<<16384, 256, 0, stream>>>(src, xf, xb);

  for (int l = 0; l < 4; ++l) {
    cvt4_k<<<12288, 256, 0, stream>>>(ipw + (size_t)l * 3145728,
                                      outw + (size_t)l * 1048576,
                                      f1w + (size_t)l * 4194304,
                                      f2w + (size_t)l * 4194304, wc);
    // QKV: [4096,3072], K=1024
    gemm8<0><<<192, 512, 0, stream>>>(xb, wc, ipb + l * 3072, qkvb, 3072, 1024, 1024, 12, 16);
    attn_f<<<dim3(8, 128), 256, 0, stream>>>(qkvb, ob);
    // out-proj: N=1024, K=1024, split-K=4
    gemm8<2><<<256, 512, 0, stream>>>(ob, wc + 3145728, nullptr, pf, 1024, 1024, 256, 4, 16);
    ln_res4_k<<<4096, 256, 0, stream>>>(xf, pf, outb + l * 1024, l1g + l * 1024, l1b + l * 1024, xf, xb);
    // FF1: [4096,4096], K=1024, ReLU
    gemm8<1><<<256, 512, 0, stream>>>(xb, wc + 4194304, f1b + l * 4096, f1o, 4096, 1024, 1024, 16, 16);
    // FF2: N=1024, K=4096, split-K=4
    gemm8<2><<<256, 512, 0, stream>>>(f1o, wc + 8388608, nullptr, pf, 1024, 4096, 1024, 4, 16);
    ln_res4_k<<<4096, 256, 0, stream>>>(xf, pf, f2b + l * 1024, l2g + l * 1024, l2b + l * 1024, xf, xb);
  }
  head_k<<<8, 256, 0, stream>>>(xf, hw, hb, (float*)d_out);
}